// Round 21
// baseline (327.455 us; speedup 1.0000x reference)
//
#include <hip/hip_runtime.h>

#define NN 512
#define BATCH 256
#define T 8
#define ATH 40

typedef unsigned long long u64;
typedef unsigned u32;
typedef unsigned char u8;
typedef unsigned short u16;

#define DEADK 512ull
#define LIVEMIN (1ull << 32)
#define UNKNOWN 0xFFFFu

__device__ __forceinline__ u64 fm(u64 a, u64 b) {
    return (u64)__double_as_longlong(fmax(__longlong_as_double((long long)a),
                                          __longlong_as_double((long long)b)));
}
__device__ __forceinline__ u64 fmn(u64 a, u64 b) {
    return (u64)__double_as_longlong(fmin(__longlong_as_double((long long)a),
                                          __longlong_as_double((long long)b)));
}

#define DPP_FMAX64(k, ctrl) do {                                              \
    int _lo = (int)(u32)(k); int _hi = (int)((k) >> 32);                      \
    int _olo = __builtin_amdgcn_update_dpp(_lo, _lo, ctrl, 0xf, 0xf, false);  \
    int _ohi = __builtin_amdgcn_update_dpp(_hi, _hi, ctrl, 0xf, 0xf, false);  \
    u64 _o = ((u64)(u32)_ohi << 32) | (u32)_olo;                              \
    (k) = fm((k), _o);                                                        \
} while (0)

#define WAVE_FMAX64(k) do {                                                   \
    DPP_FMAX64(k, 0x111); DPP_FMAX64(k, 0x112); DPP_FMAX64(k, 0x114);         \
    DPP_FMAX64(k, 0x118); DPP_FMAX64(k, 0x142); DPP_FMAX64(k, 0x143);         \
} while (0)

__device__ __forceinline__ u64 readlane64(u64 k, int l) {
    u32 lo = (u32)__builtin_amdgcn_readlane((int)(u32)k, l);
    u32 hi = (u32)__builtin_amdgcn_readlane((int)(k >> 32), l);
    return ((u64)hi << 32) | lo;
}

__device__ __forceinline__ u64 amsel(int w, u64 a0, u64 a1, u64 a2, u64 a3,
                                     u64 a4, u64 a5, u64 a6, u64 a7) {
    u64 x01 = (w & 1) ? a1 : a0;
    u64 x23 = (w & 1) ? a3 : a2;
    u64 x45 = (w & 1) ? a5 : a4;
    u64 x67 = (w & 1) ? a7 : a6;
    u64 y0 = (w & 2) ? x23 : x01;
    u64 y1 = (w & 2) ? x67 : x45;
    return (w & 4) ? y1 : y0;
}

#define INS8(X, A0, A1, A2, A3, A4, A5, A6, A7) do {                          \
    u64 _x = (X), _n;                                                         \
    _n = fm(A0, _x); _x = fmn(A0, _x); A0 = _n;                               \
    _n = fm(A1, _x); _x = fmn(A1, _x); A1 = _n;                               \
    _n = fm(A2, _x); _x = fmn(A2, _x); A2 = _n;                               \
    _n = fm(A3, _x); _x = fmn(A3, _x); A3 = _n;                               \
    _n = fm(A4, _x); _x = fmn(A4, _x); A4 = _n;                               \
    _n = fm(A5, _x); _x = fmn(A5, _x); A5 = _n;                               \
    _n = fm(A6, _x); _x = fmn(A6, _x); A6 = _n;                               \
    A7 = fm(A7, _x);                                                          \
} while (0)

#define ALIVE_C(cc) ((amsel((int)(cc) >> 6, am0,am1,am2,am3,am4,am5,am6,am7)  \
                      >> ((cc) & 63)) & 1ull)
#define ALIVE_R(rr) ((amsel((int)(rr) >> 6, ar0,ar1,ar2,ar3,ar4,ar5,ar6,ar7)  \
                      >> ((rr) & 63)) & 1ull)
#define SETK(RS, VAL) do {                                                    \
        const int rsl_ = (RS) & 63, rsj_ = (RS) >> 6;                         \
        const bool mn_ = (lane == rsl_);                                      \
        k0 = (mn_ && rsj_ == 0) ? (VAL) : k0;                                 \
        k1 = (mn_ && rsj_ == 1) ? (VAL) : k1;                                 \
        k2 = (mn_ && rsj_ == 2) ? (VAL) : k2;                                 \
        k3 = (mn_ && rsj_ == 3) ? (VAL) : k3;                                 \
        k4 = (mn_ && rsj_ == 4) ? (VAL) : k4;                                 \
        k5 = (mn_ && rsj_ == 5) ? (VAL) : k5;                                 \
        k6 = (mn_ && rsj_ == 6) ? (VAL) : k6;                                 \
        k7 = (mn_ && rsj_ == 7) ? (VAL) : k7;                                 \
    } while (0)

// wave-cooperative cold reload: top-1 among alive cols; persists into rl[RR][7]
#define COLDROW(RR, NKVAR) do {                                               \
        const float* rp_ = sb + (size_t)(RR) * NN;                            \
        const float4 fa_ = *(const float4*)(rp_ + 4 * lane);                  \
        const float4 fv_ = *(const float4*)(rp_ + 256 + 4 * lane);            \
        const int sh_ = (4 * lane) & 63; const int wq_ = lane >> 4;           \
        u64 xlo_ = (wq_ == 0) ? am0 : (wq_ == 1) ? am1 : (wq_ == 2) ? am2 : am3; \
        u64 xhi_ = (wq_ == 0) ? am4 : (wq_ == 1) ? am5 : (wq_ == 2) ? am6 : am7; \
        const u32 al8_ = ((u32)(xlo_ >> sh_) & 0xFu)                          \
                       | (((u32)(xhi_ >> sh_) & 0xFu) << 4);                  \
        u64 e0_ = (al8_ & 1u)   ? ((((u64)__float_as_uint(fa_.x) + 1) << 9) | (u32)(511 - (4*lane+0))) : 0; \
        u64 e1_ = (al8_ & 2u)   ? ((((u64)__float_as_uint(fa_.y) + 1) << 9) | (u32)(511 - (4*lane+1))) : 0; \
        u64 e2_ = (al8_ & 4u)   ? ((((u64)__float_as_uint(fa_.z) + 1) << 9) | (u32)(511 - (4*lane+2))) : 0; \
        u64 e3_ = (al8_ & 8u)   ? ((((u64)__float_as_uint(fa_.w) + 1) << 9) | (u32)(511 - (4*lane+3))) : 0; \
        u64 e4_ = (al8_ & 16u)  ? ((((u64)__float_as_uint(fv_.x) + 1) << 9) | (u32)(511 - (256+4*lane+0))) : 0; \
        u64 e5_ = (al8_ & 32u)  ? ((((u64)__float_as_uint(fv_.y) + 1) << 9) | (u32)(511 - (256+4*lane+1))) : 0; \
        u64 e6_ = (al8_ & 64u)  ? ((((u64)__float_as_uint(fv_.z) + 1) << 9) | (u32)(511 - (256+4*lane+2))) : 0; \
        u64 e7_ = (al8_ & 128u) ? ((((u64)__float_as_uint(fv_.w) + 1) << 9) | (u32)(511 - (256+4*lane+3))) : 0; \
        u64 n0_ = fm(e0_, e1_), n1_ = fm(e2_, e3_);                           \
        u64 n2_ = fm(e4_, e5_), n3_ = fm(e6_, e7_);                           \
        n0_ = fm(n0_, n1_); n2_ = fm(n2_, n3_);                               \
        u64 bw_ = fm(n0_, n2_);                                               \
        WAVE_FMAX64(bw_);                                                     \
        bw_ = readlane64(bw_, 63);                                            \
        const int wc_ = 511 - (int)(bw_ & 511);                               \
        NKVAR = ((bw_ >> 9) << 32)                                            \
              | ((u64)(u32)(512 - (RR)) << 16) | (u32)wc_;                    \
        if (lane == 0)                                                        \
            rl[RR][7] = (((bw_ >> 9) - 1ull) << 32) | (u32)wc_;               \
    } while (0)

// ---------------------------------------------------------------------------
// Kernel 1: per-ROW top-T -> slab [0,32K). Entry val<<32|col. (round-18)
// ---------------------------------------------------------------------------
__global__ __launch_bounds__(256) void build_row(const float* __restrict__ s,
                                                 float* __restrict__ out) {
    const int b = blockIdx.x >> 3;
    const int rbase = (blockIdx.x & 7) * 64;
    const int t = threadIdx.x;
    const int ct = t & 63, q = t >> 6;

    __shared__ float tile[64][65];
    __shared__ u64 mrg[64][4][8];

    const float* sb = s + (size_t)b * NN * NN;

    u64 t0 = 0, t1 = 0, t2 = 0, t3 = 0, t4 = 0, t5 = 0, t6 = 0, t7 = 0;

    for (int ch = 0; ch < 8; ++ch) {
        const int cbase = ch * 64;
        #pragma unroll
        for (int i = 0; i < 16; ++i) {
            const int rr = q + 4 * i;
            tile[rr][ct] = sb[(size_t)(rbase + rr) * NN + cbase + ct];
        }
        __syncthreads();
        #pragma unroll
        for (int i = 0; i < 16; ++i) {
            const int cc = cbase + 16 * q + i;
            const float v = tile[ct][16 * q + i];
            const u64 x = (((u64)__float_as_uint(v) + 1) << 9) | (u32)(511 - cc);
            INS8(x, t0, t1, t2, t3, t4, t5, t6, t7);
        }
        __syncthreads();
    }

    mrg[ct][q][0] = t0;  mrg[ct][q][1] = t1;  mrg[ct][q][2] = t2;
    mrg[ct][q][3] = t3;  mrg[ct][q][4] = t4;  mrg[ct][q][5] = t5;
    mrg[ct][q][6] = t6;  mrg[ct][q][7] = t7;
    __syncthreads();

    if (t < 64) {
        u64 m0 = 0, m1 = 0, m2 = 0, m3 = 0, m4 = 0, m5 = 0, m6 = 0, m7 = 0;
        #pragma unroll
        for (int qq = 0; qq < 4; ++qq)
            #pragma unroll
            for (int ii = 0; ii < 8; ++ii) {
                const u64 x = mrg[t][qq][ii];
                INS8(x, m0, m1, m2, m3, m4, m5, m6, m7);
            }
        u64* dst = (u64*)(out + (size_t)b * NN * NN) + (size_t)(rbase + t) * T;
        dst[0] = (((m0 >> 9) - 1ull) << 32) | (u32)(511 - (int)(m0 & 511));
        dst[1] = (((m1 >> 9) - 1ull) << 32) | (u32)(511 - (int)(m1 & 511));
        dst[2] = (((m2 >> 9) - 1ull) << 32) | (u32)(511 - (int)(m2 & 511));
        dst[3] = (((m3 >> 9) - 1ull) << 32) | (u32)(511 - (int)(m3 & 511));
        dst[4] = (((m4 >> 9) - 1ull) << 32) | (u32)(511 - (int)(m4 & 511));
        dst[5] = (((m5 >> 9) - 1ull) << 32) | (u32)(511 - (int)(m5 & 511));
        dst[6] = (((m6 >> 9) - 1ull) << 32) | (u32)(511 - (int)(m6 & 511));
        dst[7] = (((m7 >> 9) - 1ull) << 32) | (u32)(511 - (int)(m7 & 511));
    }
}

// ---------------------------------------------------------------------------
// Kernel 1b: per-COL top-T -> slab [32K,64K). Entry ((val+1)<<9)|(511-row).
// (round-18 proven)
// ---------------------------------------------------------------------------
__global__ __launch_bounds__(256) void build_col(const float* __restrict__ s,
                                                 float* __restrict__ out) {
    const int b = blockIdx.x >> 3;
    const int cbase = (blockIdx.x & 7) * 64;
    const int t = threadIdx.x;
    const int ct = t & 63, q = t >> 6;

    __shared__ float tile[64][65];
    __shared__ u64 mrg[64][4][8];

    const float* sb = s + (size_t)b * NN * NN;

    u64 t0 = 0, t1 = 0, t2 = 0, t3 = 0, t4 = 0, t5 = 0, t6 = 0, t7 = 0;

    for (int ch = 0; ch < 8; ++ch) {
        const int rbase = ch * 64;
        #pragma unroll
        for (int i = 0; i < 16; ++i) {
            const int rr = q + 4 * i;
            tile[rr][ct] = sb[(size_t)(rbase + rr) * NN + cbase + ct];
        }
        __syncthreads();
        #pragma unroll
        for (int i = 0; i < 16; ++i) {
            const int rr = rbase + q * 16 + i;
            const float v = tile[q * 16 + i][ct];
            const u64 x = (((u64)__float_as_uint(v) + 1) << 9) | (u32)(511 - rr);
            INS8(x, t0, t1, t2, t3, t4, t5, t6, t7);
        }
        __syncthreads();
    }

    mrg[ct][q][0] = t0;  mrg[ct][q][1] = t1;  mrg[ct][q][2] = t2;
    mrg[ct][q][3] = t3;  mrg[ct][q][4] = t4;  mrg[ct][q][5] = t5;
    mrg[ct][q][6] = t6;  mrg[ct][q][7] = t7;
    __syncthreads();

    if (t < 64) {
        u64 m0 = 0, m1 = 0, m2 = 0, m3 = 0, m4 = 0, m5 = 0, m6 = 0, m7 = 0;
        #pragma unroll
        for (int qq = 0; qq < 4; ++qq)
            #pragma unroll
            for (int ii = 0; ii < 8; ++ii) {
                const u64 x = mrg[t][qq][ii];
                INS8(x, m0, m1, m2, m3, m4, m5, m6, m7);
            }
        u64* dst = (u64*)(out + (size_t)b * NN * NN) + (size_t)NN * T
                 + (size_t)(cbase + t) * T;
        dst[0] = m0; dst[1] = m1; dst[2] = m2; dst[3] = m3;
        dst[4] = m4; dst[5] = m5; dst[6] = m6; dst[7] = m7;
    }
}

// ---------------------------------------------------------------------------
// Kernel 2a: 4-WAVE handshake phase (proven round 17).
// ---------------------------------------------------------------------------
__global__ __launch_bounds__(256) void greedy_A(const float* __restrict__ s,
                                                float* __restrict__ out,
                                                u32* __restrict__ ws_mat) {
    __shared__ __align__(16) u64 rl[NN][9];
    __shared__ __align__(16) u64 cl[NN][9];
    __shared__ __align__(16) u64 keysL[NN];
    __shared__ u32 colh[NN];
    __shared__ u8 aliveR[NN];
    __shared__ u8 aliveC[NN];
    __shared__ u16 match16[NN];
    __shared__ int cntW[4];

    const int tid = threadIdx.x;
    const int w = tid >> 6, lane = tid & 63;
    const int b = blockIdx.x;
    const float* sb = s + (size_t)b * NN * NN;
    float* ob = out + (size_t)b * NN * NN;
    u64* st = (u64*)ob + 8192;

    {
        const ulonglong2* src = (const ulonglong2*)ob;
        #pragma unroll
        for (int i = 0; i < 8; ++i) {
            const int i2 = tid + 256 * i;
            const ulonglong2 vR = src[i2];
            const ulonglong2 vC = src[2048 + i2];
            const int idx = i2 * 2;
            rl[idx >> 3][idx & 7] = vR.x;  rl[idx >> 3][(idx & 7) + 1] = vR.y;
            cl[idx >> 3][idx & 7] = vC.x;  cl[idx >> 3][(idx & 7) + 1] = vC.y;
        }
    }
    if (tid < 128) {
        ((u32*)aliveR)[tid] = 0x01010101u;
        ((u32*)aliveC)[tid] = 0x01010101u;
    }
    match16[tid] = 0; match16[tid + 256] = 0;
    __syncthreads();
    #pragma unroll
    for (int i = 0; i < 2; ++i) {
        const int r = tid + 256 * i;
        const u64 e = rl[r][0];
        keysL[r] = (((e >> 32) + 1ull) << 32)
                 | ((u64)(u32)(512 - r) << 16) | (e & 511ull);
        colh[r] = 511u - ((u32)cl[r][0] & 511u);
    }
    __syncthreads();

    u64 am0 = ~0ull, am1 = ~0ull, am2 = ~0ull, am3 = ~0ull,
        am4 = ~0ull, am5 = ~0ull, am6 = ~0ull, am7 = ~0ull;
    u64 ar0 = ~0ull, ar1 = ~0ull, ar2 = ~0ull, ar3 = ~0ull,
        ar4 = ~0ull, ar5 = ~0ull, ar6 = ~0ull, ar7 = ~0ull;

    int alive = NN;

    #pragma unroll 1
    for (int round = 0; round < 64; ++round) {
        int part = 0;
        #pragma unroll
        for (int j = 0; j < 2; ++j) {
            const int row = 128 * w + 64 * j + lane;
            const u64 kj = keysL[row];
            const u32 cc = (u32)kj & 511u;
            const bool hit = (kj >= LIVEMIN) && (colh[cc] == (u32)row);
            part += (int)__builtin_popcountll(__ballot(hit));
            if (hit) {
                match16[row] = (u16)cc;
                aliveC[cc] = 0;
                aliveR[row] = 0;
                keysL[row] = DEADK;
            }
        }
        if (lane == 0) cntW[w] = part;
        __syncthreads();                                  // B1
        const int cnt = cntW[0] + cntW[1] + cntW[2] + cntW[3];
        if (cnt == 0) break;
        alive -= cnt;

        am0 = __ballot(aliveC[lane] != 0);        am1 = __ballot(aliveC[64 + lane] != 0);
        am2 = __ballot(aliveC[128 + lane] != 0);  am3 = __ballot(aliveC[192 + lane] != 0);
        am4 = __ballot(aliveC[256 + lane] != 0);  am5 = __ballot(aliveC[320 + lane] != 0);
        am6 = __ballot(aliveC[384 + lane] != 0);  am7 = __ballot(aliveC[448 + lane] != 0);
        ar0 = __ballot(aliveR[lane] != 0);        ar1 = __ballot(aliveR[64 + lane] != 0);
        ar2 = __ballot(aliveR[128 + lane] != 0);  ar3 = __ballot(aliveR[192 + lane] != 0);
        ar4 = __ballot(aliveR[256 + lane] != 0);  ar5 = __ballot(aliveR[320 + lane] != 0);
        ar6 = __ballot(aliveR[384 + lane] != 0);  ar7 = __ballot(aliveR[448 + lane] != 0);

        if (alive <= ATH) break;

        u32 coldR = 0;
        #pragma unroll
        for (int j = 0; j < 2; ++j) {
            const int row = 128 * w + 64 * j + lane;
            const u64 kj = keysL[row];
            if (kj >= LIVEMIN && !ALIVE_C((u32)kj & 511u)) {
                const u64 f0 = rl[row][0], f1 = rl[row][1], f2 = rl[row][2];
                const u64 f3 = rl[row][3], f4 = rl[row][4], f5 = rl[row][5];
                const u64 f6 = rl[row][6], f7 = rl[row][7];
                const u64 a0 = ALIVE_C((u32)f0 & 511u);
                const u64 a1 = ALIVE_C((u32)f1 & 511u);
                const u64 a2 = ALIVE_C((u32)f2 & 511u);
                const u64 a3 = ALIVE_C((u32)f3 & 511u);
                const u64 a4 = ALIVE_C((u32)f4 & 511u);
                const u64 a5 = ALIVE_C((u32)f5 & 511u);
                const u64 a6 = ALIVE_C((u32)f6 & 511u);
                const u64 a7 = ALIVE_C((u32)f7 & 511u);
                u64 sel = 0;
                sel = a7 ? f7 : sel; sel = a6 ? f6 : sel;
                sel = a5 ? f5 : sel; sel = a4 ? f4 : sel;
                sel = a3 ? f3 : sel; sel = a2 ? f2 : sel;
                sel = a1 ? f1 : sel; sel = a0 ? f0 : sel;
                if (a0 | a1 | a2 | a3 | a4 | a5 | a6 | a7) {
                    keysL[row] = ((sel >> 32) + 1ull) << 32
                               | ((u64)(u32)(512 - row) << 16) | (sel & 511ull);
                } else coldR |= 1u << j;
            }
        }
        u64 mk = __ballot(coldR != 0u);
        while (mk) {
            const int l = (int)__builtin_ctzll(mk); mk &= mk - 1;
            u32 lm = (u32)__builtin_amdgcn_readlane((int)coldR, l);
            while (lm) {
                const int jj = (int)__builtin_ctz(lm); lm &= lm - 1;
                const int r = 128 * w + 64 * jj + l;
                u64 nkc;
                COLDROW(r, nkc);
                if (lane == 0) keysL[r] = nkc;
            }
        }

        #pragma unroll
        for (int j = 0; j < 2; ++j) {
            const int c = 128 * w + 64 * j + lane;
            const u32 chv = colh[c];
            if (aliveC[c] && chv != UNKNOWN && !ALIVE_R(chv)) {
                const u64 g0 = cl[c][0], g1 = cl[c][1], g2 = cl[c][2];
                const u64 g3 = cl[c][3], g4 = cl[c][4], g5 = cl[c][5];
                const u64 g6 = cl[c][6], g7 = cl[c][7];
                const u64 b0 = ALIVE_R(511u - ((u32)g0 & 511u));
                const u64 b1 = ALIVE_R(511u - ((u32)g1 & 511u));
                const u64 b2 = ALIVE_R(511u - ((u32)g2 & 511u));
                const u64 b3 = ALIVE_R(511u - ((u32)g3 & 511u));
                const u64 b4 = ALIVE_R(511u - ((u32)g4 & 511u));
                const u64 b5 = ALIVE_R(511u - ((u32)g5 & 511u));
                const u64 b6 = ALIVE_R(511u - ((u32)g6 & 511u));
                const u64 b7 = ALIVE_R(511u - ((u32)g7 & 511u));
                u64 sel = 0;
                sel = b7 ? g7 : sel; sel = b6 ? g6 : sel;
                sel = b5 ? g5 : sel; sel = b4 ? g4 : sel;
                sel = b3 ? g3 : sel; sel = b2 ? g2 : sel;
                sel = b1 ? g1 : sel; sel = b0 ? g0 : sel;
                colh[c] = (b0 | b1 | b2 | b3 | b4 | b5 | b6 | b7)
                        ? (511u - ((u32)sel & 511u)) : UNKNOWN;
            }
        }
        __syncthreads();                                  // B2
    }

    __syncthreads();
    st[tid] = keysL[tid];
    st[tid + 256] = keysL[tid + 256];
    if (tid < 8)
        st[512 + tid] = amsel(tid, am0, am1, am2, am3, am4, am5, am6, am7);
    ws_mat[b * 256 + tid] = ((const u32*)match16)[tid];
}

// ---------------------------------------------------------------------------
// Kernel 2b: lazy endgame + direct output write (round-20 proven).
// ---------------------------------------------------------------------------
__global__ __launch_bounds__(64) void greedy_B(const float* __restrict__ s,
                                               float* __restrict__ out,
                                               const u32* __restrict__ ws_mat) {
    __shared__ __align__(16) u64 rl[NN][8];
    __shared__ u16 match16[NN];

    const int b = blockIdx.x;
    const int lane = threadIdx.x;
    const float* sb = s + (size_t)b * NN * NN;
    float* ob = out + (size_t)b * NN * NN;
    const u64* st = (const u64*)ob + 8192;

    {
        const ulonglong2* src = (const ulonglong2*)ob;
        ulonglong2* dstl = (ulonglong2*)&rl[0][0];
        #pragma unroll
        for (int j = 0; j < 32; ++j)
            dstl[lane + 64 * j] = src[lane + 64 * j];
    }
    {
        u32* m32 = (u32*)match16;
        #pragma unroll
        for (int i = 0; i < 4; ++i)
            m32[lane + 64 * i] = ws_mat[b * 256 + lane + 64 * i];
    }

    u64 am0 = st[512], am1 = st[513], am2 = st[514], am3 = st[515];
    u64 am4 = st[516], am5 = st[517], am6 = st[518], am7 = st[519];

    u64 k0 = st[lane];        u64 k1 = st[lane + 64];
    u64 k2 = st[lane + 128];  u64 k3 = st[lane + 192];
    u64 k4 = st[lane + 256];  u64 k5 = st[lane + 320];
    u64 k6 = st[lane + 384];  u64 k7 = st[lane + 448];

    int done = NN;
    done -= (int)__builtin_popcountll(__ballot(k0 >= LIVEMIN));
    done -= (int)__builtin_popcountll(__ballot(k1 >= LIVEMIN));
    done -= (int)__builtin_popcountll(__ballot(k2 >= LIVEMIN));
    done -= (int)__builtin_popcountll(__ballot(k3 >= LIVEMIN));
    done -= (int)__builtin_popcountll(__ballot(k4 >= LIVEMIN));
    done -= (int)__builtin_popcountll(__ballot(k5 >= LIVEMIN));
    done -= (int)__builtin_popcountll(__ballot(k6 >= LIVEMIN));
    done -= (int)__builtin_popcountll(__ballot(k7 >= LIVEMIN));

    #pragma unroll 1
    while (done < NN) {
        u64 m0 = fm(k0, k1), m1 = fm(k2, k3), m2 = fm(k4, k5), m3 = fm(k6, k7);
        m0 = fm(m0, m1); m2 = fm(m2, m3);
        u64 bk = fm(m0, m2);
        WAVE_FMAX64(bk);
        const u32 lo = (u32)__builtin_amdgcn_readlane((int)(u32)bk, 63);
        const int cstar = (int)(lo & 511u);
        const int rstar = 512 - (int)((lo >> 16) & 1023u);

        const u64 e = rl[rstar][lane & 7];
        const int cw = cstar >> 6;
        const u64 aw = amsel(cw, am0, am1, am2, am3, am4, am5, am6, am7);
        const bool valid = ((aw >> (cstar & 63)) & 1ull) != 0ull;

        u64 nk;
        if (valid) {
            if (lane == 0) match16[rstar] = (u16)cstar;
            const u64 nb = ~(1ull << (cstar & 63));
            am0 = (cw == 0) ? (am0 & nb) : am0;  am1 = (cw == 1) ? (am1 & nb) : am1;
            am2 = (cw == 2) ? (am2 & nb) : am2;  am3 = (cw == 3) ? (am3 & nb) : am3;
            am4 = (cw == 4) ? (am4 & nb) : am4;  am5 = (cw == 5) ? (am5 & nb) : am5;
            am6 = (cw == 6) ? (am6 & nb) : am6;  am7 = (cw == 7) ? (am7 & nb) : am7;
            nk = DEADK;
            ++done;
        } else {
            const int c = (int)(e & 511u);
            const u64 w = amsel(c >> 6, am0, am1, am2, am3, am4, am5, am6, am7);
            const bool al = ((w >> (c & 63)) & 1ull) != 0ull;
            const u64 mask = __ballot(al) & 0xFFull;
            if (mask) {
                const u64 es = readlane64(e, (int)__builtin_ctzll(mask));
                nk = (((es >> 32) + 1ull) << 32)
                   | ((u64)(u32)(512 - rstar) << 16) | (es & 511ull);
            } else {
                COLDROW(rstar, nk);
            }
        }
        SETK(rstar, nk);
    }

    // ---- final output pass (proven): one-hot rows from match16 ----
    #pragma unroll 4
    for (int rr = 0; rr < NN; ++rr) {
        const int c = (int)match16[rr];
        float4 o0, o1;
        o0.x = (4 * lane + 0 == c) ? 1.0f : 0.0f;
        o0.y = (4 * lane + 1 == c) ? 1.0f : 0.0f;
        o0.z = (4 * lane + 2 == c) ? 1.0f : 0.0f;
        o0.w = (4 * lane + 3 == c) ? 1.0f : 0.0f;
        o1.x = (256 + 4 * lane + 0 == c) ? 1.0f : 0.0f;
        o1.y = (256 + 4 * lane + 1 == c) ? 1.0f : 0.0f;
        o1.z = (256 + 4 * lane + 2 == c) ? 1.0f : 0.0f;
        o1.w = (256 + 4 * lane + 3 == c) ? 1.0f : 0.0f;
        float* orow = ob + ((size_t)rr << 9);
        *(float4*)(orow + 4 * lane) = o0;
        *(float4*)(orow + 256 + 4 * lane) = o1;
    }
}

extern "C" void kernel_launch(void* const* d_in, const int* in_sizes, int n_in,
                              void* d_out, int out_size, void* d_ws, size_t ws_size,
                              hipStream_t stream) {
    const float* s = (const float*)d_in[0];
    float* out = (float*)d_out;
    u32* ws_mat = (u32*)d_ws;

    build_row<<<dim3(BATCH * 8), dim3(256), 0, stream>>>(s, out);
    build_col<<<dim3(BATCH * 8), dim3(256), 0, stream>>>(s, out);
    greedy_A<<<dim3(BATCH), dim3(256), 0, stream>>>(s, out, ws_mat);
    greedy_B<<<dim3(BATCH), dim3(64), 0, stream>>>(s, out, ws_mat);
}

// Round 22
// 279.957 us; speedup vs baseline: 1.1697x; 1.1697x over previous
//
#include <hip/hip_runtime.h>

#define NN 512
#define BATCH 256
#define T 8
#define ATH 40

typedef unsigned long long u64;
typedef unsigned u32;
typedef unsigned char u8;
typedef unsigned short u16;

#define DEADK 512ull
#define LIVEMIN (1ull << 32)
#define UNKNOWN 0xFFFFu

__device__ __forceinline__ u64 fm(u64 a, u64 b) {
    return (u64)__double_as_longlong(fmax(__longlong_as_double((long long)a),
                                          __longlong_as_double((long long)b)));
}
__device__ __forceinline__ u64 fmn(u64 a, u64 b) {
    return (u64)__double_as_longlong(fmin(__longlong_as_double((long long)a),
                                          __longlong_as_double((long long)b)));
}

#define DPP_FMAX64(k, ctrl) do {                                              \
    int _lo = (int)(u32)(k); int _hi = (int)((k) >> 32);                      \
    int _olo = __builtin_amdgcn_update_dpp(_lo, _lo, ctrl, 0xf, 0xf, false);  \
    int _ohi = __builtin_amdgcn_update_dpp(_hi, _hi, ctrl, 0xf, 0xf, false);  \
    u64 _o = ((u64)(u32)_ohi << 32) | (u32)_olo;                              \
    (k) = fm((k), _o);                                                        \
} while (0)

#define WAVE_FMAX64(k) do {                                                   \
    DPP_FMAX64(k, 0x111); DPP_FMAX64(k, 0x112); DPP_FMAX64(k, 0x114);         \
    DPP_FMAX64(k, 0x118); DPP_FMAX64(k, 0x142); DPP_FMAX64(k, 0x143);         \
} while (0)

__device__ __forceinline__ u64 readlane64(u64 k, int l) {
    u32 lo = (u32)__builtin_amdgcn_readlane((int)(u32)k, l);
    u32 hi = (u32)__builtin_amdgcn_readlane((int)(k >> 32), l);
    return ((u64)hi << 32) | lo;
}

__device__ __forceinline__ u64 amsel(int w, u64 a0, u64 a1, u64 a2, u64 a3,
                                     u64 a4, u64 a5, u64 a6, u64 a7) {
    u64 x01 = (w & 1) ? a1 : a0;
    u64 x23 = (w & 1) ? a3 : a2;
    u64 x45 = (w & 1) ? a5 : a4;
    u64 x67 = (w & 1) ? a7 : a6;
    u64 y0 = (w & 2) ? x23 : x01;
    u64 y1 = (w & 2) ? x67 : x45;
    return (w & 4) ? y1 : y0;
}

#define INS8(X, A0, A1, A2, A3, A4, A5, A6, A7) do {                          \
    u64 _x = (X), _n;                                                         \
    _n = fm(A0, _x); _x = fmn(A0, _x); A0 = _n;                               \
    _n = fm(A1, _x); _x = fmn(A1, _x); A1 = _n;                               \
    _n = fm(A2, _x); _x = fmn(A2, _x); A2 = _n;                               \
    _n = fm(A3, _x); _x = fmn(A3, _x); A3 = _n;                               \
    _n = fm(A4, _x); _x = fmn(A4, _x); A4 = _n;                               \
    _n = fm(A5, _x); _x = fmn(A5, _x); A5 = _n;                               \
    _n = fm(A6, _x); _x = fmn(A6, _x); A6 = _n;                               \
    A7 = fm(A7, _x);                                                          \
} while (0)

#define ALIVE_C(cc) ((amsel((int)(cc) >> 6, am0,am1,am2,am3,am4,am5,am6,am7)  \
                      >> ((cc) & 63)) & 1ull)
#define ALIVE_R(rr) ((amsel((int)(rr) >> 6, ar0,ar1,ar2,ar3,ar4,ar5,ar6,ar7)  \
                      >> ((rr) & 63)) & 1ull)
#define SETK(RS, VAL) do {                                                    \
        const int rsl_ = (RS) & 63, rsj_ = (RS) >> 6;                         \
        const bool mn_ = (lane == rsl_);                                      \
        k0 = (mn_ && rsj_ == 0) ? (VAL) : k0;                                 \
        k1 = (mn_ && rsj_ == 1) ? (VAL) : k1;                                 \
        k2 = (mn_ && rsj_ == 2) ? (VAL) : k2;                                 \
        k3 = (mn_ && rsj_ == 3) ? (VAL) : k3;                                 \
        k4 = (mn_ && rsj_ == 4) ? (VAL) : k4;                                 \
        k5 = (mn_ && rsj_ == 5) ? (VAL) : k5;                                 \
        k6 = (mn_ && rsj_ == 6) ? (VAL) : k6;                                 \
        k7 = (mn_ && rsj_ == 7) ? (VAL) : k7;                                 \
    } while (0)

// wave-cooperative cold reload: top-1 among alive cols; persists into rl[RR][7]
#define COLDROW(RR, NKVAR) do {                                               \
        const float* rp_ = sb + (size_t)(RR) * NN;                            \
        const float4 fa_ = *(const float4*)(rp_ + 4 * lane);                  \
        const float4 fv_ = *(const float4*)(rp_ + 256 + 4 * lane);            \
        const int sh_ = (4 * lane) & 63; const int wq_ = lane >> 4;           \
        u64 xlo_ = (wq_ == 0) ? am0 : (wq_ == 1) ? am1 : (wq_ == 2) ? am2 : am3; \
        u64 xhi_ = (wq_ == 0) ? am4 : (wq_ == 1) ? am5 : (wq_ == 2) ? am6 : am7; \
        const u32 al8_ = ((u32)(xlo_ >> sh_) & 0xFu)                          \
                       | (((u32)(xhi_ >> sh_) & 0xFu) << 4);                  \
        u64 e0_ = (al8_ & 1u)   ? ((((u64)__float_as_uint(fa_.x) + 1) << 9) | (u32)(511 - (4*lane+0))) : 0; \
        u64 e1_ = (al8_ & 2u)   ? ((((u64)__float_as_uint(fa_.y) + 1) << 9) | (u32)(511 - (4*lane+1))) : 0; \
        u64 e2_ = (al8_ & 4u)   ? ((((u64)__float_as_uint(fa_.z) + 1) << 9) | (u32)(511 - (4*lane+2))) : 0; \
        u64 e3_ = (al8_ & 8u)   ? ((((u64)__float_as_uint(fa_.w) + 1) << 9) | (u32)(511 - (4*lane+3))) : 0; \
        u64 e4_ = (al8_ & 16u)  ? ((((u64)__float_as_uint(fv_.x) + 1) << 9) | (u32)(511 - (256+4*lane+0))) : 0; \
        u64 e5_ = (al8_ & 32u)  ? ((((u64)__float_as_uint(fv_.y) + 1) << 9) | (u32)(511 - (256+4*lane+1))) : 0; \
        u64 e6_ = (al8_ & 64u)  ? ((((u64)__float_as_uint(fv_.z) + 1) << 9) | (u32)(511 - (256+4*lane+2))) : 0; \
        u64 e7_ = (al8_ & 128u) ? ((((u64)__float_as_uint(fv_.w) + 1) << 9) | (u32)(511 - (256+4*lane+3))) : 0; \
        u64 n0_ = fm(e0_, e1_), n1_ = fm(e2_, e3_);                           \
        u64 n2_ = fm(e4_, e5_), n3_ = fm(e6_, e7_);                           \
        n0_ = fm(n0_, n1_); n2_ = fm(n2_, n3_);                               \
        u64 bw_ = fm(n0_, n2_);                                               \
        WAVE_FMAX64(bw_);                                                     \
        bw_ = readlane64(bw_, 63);                                            \
        const int wc_ = 511 - (int)(bw_ & 511);                               \
        NKVAR = ((bw_ >> 9) << 32)                                            \
              | ((u64)(u32)(512 - (RR)) << 16) | (u32)wc_;                    \
        if (lane == 0)                                                        \
            rl[RR][7] = (((bw_ >> 9) - 1ull) << 32) | (u32)wc_;               \
    } while (0)

// ---------------------------------------------------------------------------
// Kernel 1: per-ROW top-T -> slab [0,32K). Entry val<<32|col. (round-18)
// ---------------------------------------------------------------------------
__global__ __launch_bounds__(256) void build_row(const float* __restrict__ s,
                                                 float* __restrict__ out) {
    const int b = blockIdx.x >> 3;
    const int rbase = (blockIdx.x & 7) * 64;
    const int t = threadIdx.x;
    const int ct = t & 63, q = t >> 6;

    __shared__ float tile[64][65];
    __shared__ u64 mrg[64][4][8];

    const float* sb = s + (size_t)b * NN * NN;

    u64 t0 = 0, t1 = 0, t2 = 0, t3 = 0, t4 = 0, t5 = 0, t6 = 0, t7 = 0;

    for (int ch = 0; ch < 8; ++ch) {
        const int cbase = ch * 64;
        #pragma unroll
        for (int i = 0; i < 16; ++i) {
            const int rr = q + 4 * i;
            tile[rr][ct] = sb[(size_t)(rbase + rr) * NN + cbase + ct];
        }
        __syncthreads();
        #pragma unroll
        for (int i = 0; i < 16; ++i) {
            const int cc = cbase + 16 * q + i;
            const float v = tile[ct][16 * q + i];
            const u64 x = (((u64)__float_as_uint(v) + 1) << 9) | (u32)(511 - cc);
            INS8(x, t0, t1, t2, t3, t4, t5, t6, t7);
        }
        __syncthreads();
    }

    mrg[ct][q][0] = t0;  mrg[ct][q][1] = t1;  mrg[ct][q][2] = t2;
    mrg[ct][q][3] = t3;  mrg[ct][q][4] = t4;  mrg[ct][q][5] = t5;
    mrg[ct][q][6] = t6;  mrg[ct][q][7] = t7;
    __syncthreads();

    if (t < 64) {
        u64 m0 = 0, m1 = 0, m2 = 0, m3 = 0, m4 = 0, m5 = 0, m6 = 0, m7 = 0;
        #pragma unroll
        for (int qq = 0; qq < 4; ++qq)
            #pragma unroll
            for (int ii = 0; ii < 8; ++ii) {
                const u64 x = mrg[t][qq][ii];
                INS8(x, m0, m1, m2, m3, m4, m5, m6, m7);
            }
        u64* dst = (u64*)(out + (size_t)b * NN * NN) + (size_t)(rbase + t) * T;
        dst[0] = (((m0 >> 9) - 1ull) << 32) | (u32)(511 - (int)(m0 & 511));
        dst[1] = (((m1 >> 9) - 1ull) << 32) | (u32)(511 - (int)(m1 & 511));
        dst[2] = (((m2 >> 9) - 1ull) << 32) | (u32)(511 - (int)(m2 & 511));
        dst[3] = (((m3 >> 9) - 1ull) << 32) | (u32)(511 - (int)(m3 & 511));
        dst[4] = (((m4 >> 9) - 1ull) << 32) | (u32)(511 - (int)(m4 & 511));
        dst[5] = (((m5 >> 9) - 1ull) << 32) | (u32)(511 - (int)(m5 & 511));
        dst[6] = (((m6 >> 9) - 1ull) << 32) | (u32)(511 - (int)(m6 & 511));
        dst[7] = (((m7 >> 9) - 1ull) << 32) | (u32)(511 - (int)(m7 & 511));
    }
}

// ---------------------------------------------------------------------------
// Kernel 1b: per-COL top-T -> slab [32K,64K). Entry ((val+1)<<9)|(511-row).
// (round-18 proven)
// ---------------------------------------------------------------------------
__global__ __launch_bounds__(256) void build_col(const float* __restrict__ s,
                                                 float* __restrict__ out) {
    const int b = blockIdx.x >> 3;
    const int cbase = (blockIdx.x & 7) * 64;
    const int t = threadIdx.x;
    const int ct = t & 63, q = t >> 6;

    __shared__ float tile[64][65];
    __shared__ u64 mrg[64][4][8];

    const float* sb = s + (size_t)b * NN * NN;

    u64 t0 = 0, t1 = 0, t2 = 0, t3 = 0, t4 = 0, t5 = 0, t6 = 0, t7 = 0;

    for (int ch = 0; ch < 8; ++ch) {
        const int rbase = ch * 64;
        #pragma unroll
        for (int i = 0; i < 16; ++i) {
            const int rr = q + 4 * i;
            tile[rr][ct] = sb[(size_t)(rbase + rr) * NN + cbase + ct];
        }
        __syncthreads();
        #pragma unroll
        for (int i = 0; i < 16; ++i) {
            const int rr = rbase + q * 16 + i;
            const float v = tile[q * 16 + i][ct];
            const u64 x = (((u64)__float_as_uint(v) + 1) << 9) | (u32)(511 - rr);
            INS8(x, t0, t1, t2, t3, t4, t5, t6, t7);
        }
        __syncthreads();
    }

    mrg[ct][q][0] = t0;  mrg[ct][q][1] = t1;  mrg[ct][q][2] = t2;
    mrg[ct][q][3] = t3;  mrg[ct][q][4] = t4;  mrg[ct][q][5] = t5;
    mrg[ct][q][6] = t6;  mrg[ct][q][7] = t7;
    __syncthreads();

    if (t < 64) {
        u64 m0 = 0, m1 = 0, m2 = 0, m3 = 0, m4 = 0, m5 = 0, m6 = 0, m7 = 0;
        #pragma unroll
        for (int qq = 0; qq < 4; ++qq)
            #pragma unroll
            for (int ii = 0; ii < 8; ++ii) {
                const u64 x = mrg[t][qq][ii];
                INS8(x, m0, m1, m2, m3, m4, m5, m6, m7);
            }
        u64* dst = (u64*)(out + (size_t)b * NN * NN) + (size_t)NN * T
                 + (size_t)(cbase + t) * T;
        dst[0] = m0; dst[1] = m1; dst[2] = m2; dst[3] = m3;
        dst[4] = m4; dst[5] = m5; dst[6] = m6; dst[7] = m7;
    }
}

// ---------------------------------------------------------------------------
// Kernel 2a: 8-WAVE handshake phase. Wave w owns rows/cols [64w, 64w+64).
// Same barrier structure & safety argument as the proven 4-wave version:
// per-col aliveC writes unique (colh single-valued); colh reads (DET) vs
// writes (REPC) separated by B2; exits uniform via shared cntW/alive.
// ---------------------------------------------------------------------------
__global__ __launch_bounds__(512) void greedy_A(const float* __restrict__ s,
                                                float* __restrict__ out,
                                                u32* __restrict__ ws_mat) {
    __shared__ __align__(16) u64 rl[NN][9];
    __shared__ __align__(16) u64 cl[NN][9];
    __shared__ __align__(16) u64 keysL[NN];
    __shared__ u32 colh[NN];
    __shared__ u8 aliveR[NN];
    __shared__ u8 aliveC[NN];
    __shared__ u16 match16[NN];
    __shared__ int cntW[8];

    const int tid = threadIdx.x;
    const int w = tid >> 6, lane = tid & 63;
    const int b = blockIdx.x;
    const float* sb = s + (size_t)b * NN * NN;
    float* ob = out + (size_t)b * NN * NN;
    u64* st = (u64*)ob + 8192;

    {
        const ulonglong2* src = (const ulonglong2*)ob;
        #pragma unroll
        for (int i = 0; i < 4; ++i) {
            const int i2 = tid + 512 * i;
            const ulonglong2 vR = src[i2];
            const ulonglong2 vC = src[2048 + i2];
            const int idx = i2 * 2;
            rl[idx >> 3][idx & 7] = vR.x;  rl[idx >> 3][(idx & 7) + 1] = vR.y;
            cl[idx >> 3][idx & 7] = vC.x;  cl[idx >> 3][(idx & 7) + 1] = vC.y;
        }
    }
    if (tid < 128) {
        ((u32*)aliveR)[tid] = 0x01010101u;
        ((u32*)aliveC)[tid] = 0x01010101u;
    }
    match16[tid] = 0;
    __syncthreads();
    {
        const u64 e = rl[tid][0];
        keysL[tid] = (((e >> 32) + 1ull) << 32)
                   | ((u64)(u32)(512 - tid) << 16) | (e & 511ull);
        colh[tid] = 511u - ((u32)cl[tid][0] & 511u);
    }
    __syncthreads();

    u64 am0 = ~0ull, am1 = ~0ull, am2 = ~0ull, am3 = ~0ull,
        am4 = ~0ull, am5 = ~0ull, am6 = ~0ull, am7 = ~0ull;
    u64 ar0 = ~0ull, ar1 = ~0ull, ar2 = ~0ull, ar3 = ~0ull,
        ar4 = ~0ull, ar5 = ~0ull, ar6 = ~0ull, ar7 = ~0ull;

    int alive = NN;
    const int row = 64 * w + lane;      // this thread's owned row & col index

    #pragma unroll 1
    for (int round = 0; round < 64; ++round) {
        // ---- DET + CMT on own row ----
        {
            const u64 kj = keysL[row];
            const u32 cc = (u32)kj & 511u;
            const bool hit = (kj >= LIVEMIN) && (colh[cc] == (u32)row);
            const int part = (int)__builtin_popcountll(__ballot(hit));
            if (hit) {
                match16[row] = (u16)cc;
                aliveC[cc] = 0;
                aliveR[row] = 0;
                keysL[row] = DEADK;
            }
            if (lane == 0) cntW[w] = part;
        }
        __syncthreads();                                  // B1
        const int cnt = cntW[0] + cntW[1] + cntW[2] + cntW[3]
                      + cntW[4] + cntW[5] + cntW[6] + cntW[7];
        if (cnt == 0) break;
        alive -= cnt;

        am0 = __ballot(aliveC[lane] != 0);        am1 = __ballot(aliveC[64 + lane] != 0);
        am2 = __ballot(aliveC[128 + lane] != 0);  am3 = __ballot(aliveC[192 + lane] != 0);
        am4 = __ballot(aliveC[256 + lane] != 0);  am5 = __ballot(aliveC[320 + lane] != 0);
        am6 = __ballot(aliveC[384 + lane] != 0);  am7 = __ballot(aliveC[448 + lane] != 0);
        ar0 = __ballot(aliveR[lane] != 0);        ar1 = __ballot(aliveR[64 + lane] != 0);
        ar2 = __ballot(aliveR[128 + lane] != 0);  ar3 = __ballot(aliveR[192 + lane] != 0);
        ar4 = __ballot(aliveR[256 + lane] != 0);  ar5 = __ballot(aliveR[320 + lane] != 0);
        ar6 = __ballot(aliveR[384 + lane] != 0);  ar7 = __ballot(aliveR[448 + lane] != 0);

        if (alive <= ATH) break;

        // ---- REPR on own row ----
        bool coldR = false;
        {
            const u64 kj = keysL[row];
            if (kj >= LIVEMIN && !ALIVE_C((u32)kj & 511u)) {
                const u64 f0 = rl[row][0], f1 = rl[row][1], f2 = rl[row][2];
                const u64 f3 = rl[row][3], f4 = rl[row][4], f5 = rl[row][5];
                const u64 f6 = rl[row][6], f7 = rl[row][7];
                const u64 a0 = ALIVE_C((u32)f0 & 511u);
                const u64 a1 = ALIVE_C((u32)f1 & 511u);
                const u64 a2 = ALIVE_C((u32)f2 & 511u);
                const u64 a3 = ALIVE_C((u32)f3 & 511u);
                const u64 a4 = ALIVE_C((u32)f4 & 511u);
                const u64 a5 = ALIVE_C((u32)f5 & 511u);
                const u64 a6 = ALIVE_C((u32)f6 & 511u);
                const u64 a7 = ALIVE_C((u32)f7 & 511u);
                u64 sel = 0;
                sel = a7 ? f7 : sel; sel = a6 ? f6 : sel;
                sel = a5 ? f5 : sel; sel = a4 ? f4 : sel;
                sel = a3 ? f3 : sel; sel = a2 ? f2 : sel;
                sel = a1 ? f1 : sel; sel = a0 ? f0 : sel;
                if (a0 | a1 | a2 | a3 | a4 | a5 | a6 | a7) {
                    keysL[row] = ((sel >> 32) + 1ull) << 32
                               | ((u64)(u32)(512 - row) << 16) | (sel & 511ull);
                } else coldR = true;
            }
        }
        // colds: 8 waves run their own reloads concurrently
        u64 mk = __ballot(coldR);
        while (mk) {
            const int l = (int)__builtin_ctzll(mk); mk &= mk - 1;
            const int r = 64 * w + l;
            u64 nkc;
            COLDROW(r, nkc);
            if (lane == 0) keysL[r] = nkc;
        }

        // ---- REPC on own col ----
        {
            const int c = row;
            const u32 chv = colh[c];
            if (aliveC[c] && chv != UNKNOWN && !ALIVE_R(chv)) {
                const u64 g0 = cl[c][0], g1 = cl[c][1], g2 = cl[c][2];
                const u64 g3 = cl[c][3], g4 = cl[c][4], g5 = cl[c][5];
                const u64 g6 = cl[c][6], g7 = cl[c][7];
                const u64 b0 = ALIVE_R(511u - ((u32)g0 & 511u));
                const u64 b1 = ALIVE_R(511u - ((u32)g1 & 511u));
                const u64 b2 = ALIVE_R(511u - ((u32)g2 & 511u));
                const u64 b3 = ALIVE_R(511u - ((u32)g3 & 511u));
                const u64 b4 = ALIVE_R(511u - ((u32)g4 & 511u));
                const u64 b5 = ALIVE_R(511u - ((u32)g5 & 511u));
                const u64 b6 = ALIVE_R(511u - ((u32)g6 & 511u));
                const u64 b7 = ALIVE_R(511u - ((u32)g7 & 511u));
                u64 sel = 0;
                sel = b7 ? g7 : sel; sel = b6 ? g6 : sel;
                sel = b5 ? g5 : sel; sel = b4 ? g4 : sel;
                sel = b3 ? g3 : sel; sel = b2 ? g2 : sel;
                sel = b1 ? g1 : sel; sel = b0 ? g0 : sel;
                colh[c] = (b0 | b1 | b2 | b3 | b4 | b5 | b6 | b7)
                        ? (511u - ((u32)sel & 511u)) : UNKNOWN;
            }
        }
        __syncthreads();                                  // B2
    }

    __syncthreads();
    st[tid] = keysL[tid];
    if (tid < 8)
        st[512 + tid] = amsel(tid, am0, am1, am2, am3, am4, am5, am6, am7);
    if (tid < 256)
        ws_mat[b * 256 + tid] = ((const u32*)match16)[tid];
}

// ---------------------------------------------------------------------------
// Kernel 2b: lazy endgame (round-18 proven; match16 -> ws_mat).
// ---------------------------------------------------------------------------
__global__ __launch_bounds__(64) void greedy_B(const float* __restrict__ s,
                                               const float* __restrict__ out,
                                               u32* __restrict__ ws_mat) {
    __shared__ __align__(16) u64 rl[NN][8];
    __shared__ u16 match16[NN];

    const int b = blockIdx.x;
    const int lane = threadIdx.x;
    const float* sb = s + (size_t)b * NN * NN;
    const float* ob = out + (size_t)b * NN * NN;
    const u64* st = (const u64*)ob + 8192;

    {
        const ulonglong2* src = (const ulonglong2*)ob;
        ulonglong2* dstl = (ulonglong2*)&rl[0][0];
        #pragma unroll
        for (int j = 0; j < 32; ++j)
            dstl[lane + 64 * j] = src[lane + 64 * j];
    }
    {
        u32* m32 = (u32*)match16;
        #pragma unroll
        for (int i = 0; i < 4; ++i)
            m32[lane + 64 * i] = ws_mat[b * 256 + lane + 64 * i];
    }

    u64 am0 = st[512], am1 = st[513], am2 = st[514], am3 = st[515];
    u64 am4 = st[516], am5 = st[517], am6 = st[518], am7 = st[519];

    u64 k0 = st[lane];        u64 k1 = st[lane + 64];
    u64 k2 = st[lane + 128];  u64 k3 = st[lane + 192];
    u64 k4 = st[lane + 256];  u64 k5 = st[lane + 320];
    u64 k6 = st[lane + 384];  u64 k7 = st[lane + 448];

    int done = NN;
    done -= (int)__builtin_popcountll(__ballot(k0 >= LIVEMIN));
    done -= (int)__builtin_popcountll(__ballot(k1 >= LIVEMIN));
    done -= (int)__builtin_popcountll(__ballot(k2 >= LIVEMIN));
    done -= (int)__builtin_popcountll(__ballot(k3 >= LIVEMIN));
    done -= (int)__builtin_popcountll(__ballot(k4 >= LIVEMIN));
    done -= (int)__builtin_popcountll(__ballot(k5 >= LIVEMIN));
    done -= (int)__builtin_popcountll(__ballot(k6 >= LIVEMIN));
    done -= (int)__builtin_popcountll(__ballot(k7 >= LIVEMIN));

    #pragma unroll 1
    while (done < NN) {
        u64 m0 = fm(k0, k1), m1 = fm(k2, k3), m2 = fm(k4, k5), m3 = fm(k6, k7);
        m0 = fm(m0, m1); m2 = fm(m2, m3);
        u64 bk = fm(m0, m2);
        WAVE_FMAX64(bk);
        const u32 lo = (u32)__builtin_amdgcn_readlane((int)(u32)bk, 63);
        const int cstar = (int)(lo & 511u);
        const int rstar = 512 - (int)((lo >> 16) & 1023u);

        const u64 e = rl[rstar][lane & 7];
        const int cw = cstar >> 6;
        const u64 aw = amsel(cw, am0, am1, am2, am3, am4, am5, am6, am7);
        const bool valid = ((aw >> (cstar & 63)) & 1ull) != 0ull;

        u64 nk;
        if (valid) {
            if (lane == 0) match16[rstar] = (u16)cstar;
            const u64 nb = ~(1ull << (cstar & 63));
            am0 = (cw == 0) ? (am0 & nb) : am0;  am1 = (cw == 1) ? (am1 & nb) : am1;
            am2 = (cw == 2) ? (am2 & nb) : am2;  am3 = (cw == 3) ? (am3 & nb) : am3;
            am4 = (cw == 4) ? (am4 & nb) : am4;  am5 = (cw == 5) ? (am5 & nb) : am5;
            am6 = (cw == 6) ? (am6 & nb) : am6;  am7 = (cw == 7) ? (am7 & nb) : am7;
            nk = DEADK;
            ++done;
        } else {
            const int c = (int)(e & 511u);
            const u64 w = amsel(c >> 6, am0, am1, am2, am3, am4, am5, am6, am7);
            const bool al = ((w >> (c & 63)) & 1ull) != 0ull;
            const u64 mask = __ballot(al) & 0xFFull;
            if (mask) {
                const u64 es = readlane64(e, (int)__builtin_ctzll(mask));
                nk = (((es >> 32) + 1ull) << 32)
                   | ((u64)(u32)(512 - rstar) << 16) | (es & 511ull);
            } else {
                COLDROW(rstar, nk);
            }
        }
        SETK(rstar, nk);
    }

    {
        const u32* m32 = (const u32*)match16;
        #pragma unroll
        for (int i = 0; i < 4; ++i)
            ws_mat[b * 256 + lane + 64 * i] = m32[lane + 64 * i];
    }
}

// ---------------------------------------------------------------------------
// Kernel 3: fully parallel one-hot output from match16 (stride 256 u32).
// ---------------------------------------------------------------------------
__global__ __launch_bounds__(256) void write_out(const u32* __restrict__ ws_mat,
                                                 float* __restrict__ out) {
    const int gid = blockIdx.x * 256 + threadIdx.x;
    const int b = gid >> 16;
    const int rem = gid & 65535;
    const int row = rem >> 7;
    const int quad = rem & 127;
    const u32 w = ws_mat[b * 256 + (row >> 1)];
    const int c = (int)((w >> (16 * (row & 1))) & 0xFFFFu);
    float4 f;
    f.x = (c == quad * 4 + 0) ? 1.0f : 0.0f;
    f.y = (c == quad * 4 + 1) ? 1.0f : 0.0f;
    f.z = (c == quad * 4 + 2) ? 1.0f : 0.0f;
    f.w = (c == quad * 4 + 3) ? 1.0f : 0.0f;
    ((float4*)out)[gid] = f;
}

extern "C" void kernel_launch(void* const* d_in, const int* in_sizes, int n_in,
                              void* d_out, int out_size, void* d_ws, size_t ws_size,
                              hipStream_t stream) {
    const float* s = (const float*)d_in[0];
    float* out = (float*)d_out;
    u32* ws_mat = (u32*)d_ws;

    build_row<<<dim3(BATCH * 8), dim3(256), 0, stream>>>(s, out);
    build_col<<<dim3(BATCH * 8), dim3(256), 0, stream>>>(s, out);
    greedy_A<<<dim3(BATCH), dim3(512), 0, stream>>>(s, out, ws_mat);
    greedy_B<<<dim3(BATCH), dim3(64), 0, stream>>>(s, out, ws_mat);
    write_out<<<dim3(BATCH * 256), dim3(256), 0, stream>>>(ws_mat, out);
}